// Round 8
// baseline (354.740 us; speedup 1.0000x reference)
//
#include <hip/hip_runtime.h>
#include <hip/hip_bf16.h>
#include <math.h>

#define NB 2
#define C 64
#define H 256
#define W 256
#define HIN 512
#define WIN 512
#define CIN 64
#define G 4
#define P 9
#define GC 16
#define NPIX (NB*H*W)   // 131072

typedef __attribute__((ext_vector_type(8))) __bf16 bf16x8v;
typedef __attribute__((ext_vector_type(4))) float floatx4;

// ws float offsets
#define O_WOUT   47872    // w_out MFMA B-frags: wh[4096 bf16] | wl[4096 bf16] = 4096 floats
#define O_BIN    51968    // 64
#define O_DWW    52032    // 576
#define O_DWB    52608    // 64
#define O_LNG    52672    // 64
#define O_LNB    52736    // 64
#define O_BOFF   52800    // 72
#define O_BMASK  52872    // 36
#define O_BOUT   52908    // 64
#define O_WFRAG  53248    // conv MFMA B-frags: 36864 bf16 = 18432 floats -> end 71680
#define O_WINF   71680    // w_in MFMA B-frags: 4096 bf16 = 2048 floats  -> end 73728
#define O_WCOMB  73728    // [w_off|w_mask|pad] 64x112 B-frags: 7168 bf16 = 3584 floats -> 77312
#define O_Y      77824    // 8388608 fp32 NHWC conv output
#define O_XP     (O_Y  + 8388608)
#define O_OFFS   (O_XP + 8388608)   // 9437184
#define O_MASK   (O_OFFS + 9437184) // 4718592
// xt (bf16 NHWC, 16777216 floats) overlaps [O_XP, O_XP+16777216): dead after conv;
// xp (written by k_branch, AFTER conv) / offs land there in stream order. Safe.

static __device__ __forceinline__ unsigned pkbf(float a, float b) {
    unsigned lo = __bfloat16_as_ushort(__float2bfloat16(a));
    unsigned hi = __bfloat16_as_ushort(__float2bfloat16(b));
    return lo | (hi << 16);
}

// ---------------- K0: stage weights/biases + pack all MFMA B-fragments ----------------
__global__ void k_prep(const float* __restrict__ conv_w, const float* __restrict__ w_in,
                       const float* __restrict__ b_in,
                       const float* __restrict__ dw_w, const float* __restrict__ dw_b,
                       const float* __restrict__ ln_g, const float* __restrict__ ln_b,
                       const float* __restrict__ w_off, const float* __restrict__ b_off,
                       const float* __restrict__ w_mask, const float* __restrict__ b_mask,
                       const float* __restrict__ w_out, const float* __restrict__ b_out,
                       float* __restrict__ ws)
{
    int i = blockIdx.x*256 + threadIdx.x;
    if (i < 36864) {   // conv B-frags: idx = ((tap*2+ks)*4+nt)*512 + lane*8 + j
        int j    = i & 7;
        int lane = (i >> 3) & 63;
        int nt   = (i >> 9) & 3;
        int ks   = (i >> 11) & 1;
        int tap  = i >> 12;
        int kh = tap / 3, kw = tap % 3;
        int ci = ks*32 + (lane >> 4)*8 + j;
        int co = nt*16 + (lane & 15);
        ((__hip_bfloat16*)(ws + O_WFRAG))[i] =
            __float2bfloat16(conv_w[co*576 + ci*9 + kh*3 + kw]);
    }
    if (i < 4096) {    // w_in B-frags: idx = (ks*4+nt)*512 + lane*8 + j
        int j    = i & 7;
        int lane = (i >> 3) & 63;
        int s    = i >> 9;
        int nt   = s & 3, ks = s >> 2;
        int ci = ks*32 + (lane >> 4)*8 + j;
        int co = nt*16 + (lane & 15);
        ((__hip_bfloat16*)(ws + O_WINF))[i] = __float2bfloat16(w_in[ci*64 + co]);
    }
    if (i < 4096) {    // w_out split-fp32 B-frags (hi|lo), same frag layout as O_WINF
        int j    = i & 7;
        int lane = (i >> 3) & 63;
        int s    = i >> 9;
        int nt   = s & 3, ks = s >> 2;
        int ci = ks*32 + (lane >> 4)*8 + j;
        int co = nt*16 + (lane & 15);
        float w = w_out[ci*64 + co];
        __hip_bfloat16 h = __float2bfloat16(w);
        ((__hip_bfloat16*)(ws + O_WOUT))[i]        = h;
        ((__hip_bfloat16*)(ws + O_WOUT))[4096 + i] = __float2bfloat16(w - __bfloat162float(h));
    }
    if (i < 7168) {    // combined off|mask B-frags: idx = (ks*7+nt)*512 + lane*8 + j
        int j    = i & 7;
        int lane = (i >> 3) & 63;
        int s    = i >> 9;          // 0..13
        int nt   = s % 7, ks = s / 7;
        int ci = ks*32 + (lane >> 4)*8 + j;
        int jj = nt*16 + (lane & 15);
        float v = (jj < 72) ? w_off[ci*72 + jj] : (jj < 108 ? w_mask[ci*36 + (jj-72)] : 0.f);
        ((__hip_bfloat16*)(ws + O_WCOMB))[i] = __float2bfloat16(v);
    }
    if (i < 64)   ws[O_BIN  + i] = b_in[i];
    if (i < 576)  ws[O_DWW  + i] = dw_w[i];
    if (i < 64)   ws[O_DWB  + i] = dw_b[i];
    if (i < 64)   ws[O_LNG  + i] = ln_g[i];
    if (i < 64)   ws[O_LNB  + i] = ln_b[i];
    if (i < 72)   ws[O_BOFF + i] = b_off[i];
    if (i < 36)   ws[O_BMASK+ i] = b_mask[i];
    if (i < 64)   ws[O_BOUT + i] = b_out[i];
}

// ---------------- K1a: x fp32 NCHW -> xt bf16 NHWC (LDS tile transpose) ---------------
__global__ __launch_bounds__(256) void k_xt(
    const float* __restrict__ x, __hip_bfloat16* __restrict__ xt)
{
    __shared__ float tile[64][65];
    int t = threadIdx.x;
    int b = blockIdx.x;
    int n  = b >> 12;
    int p0 = (b & 4095) * 64;
    const float* xb = x + (size_t)n*CIN*262144 + p0;
    #pragma unroll
    for (int k=0;k<4;k++) {
        int ch = k*16 + (t>>4);
        int p4 = (t&15)*4;
        float4 v = *(const float4*)(xb + (size_t)ch*262144 + p4);
        tile[p4+0][ch] = v.x;
        tile[p4+1][ch] = v.y;
        tile[p4+2][ch] = v.z;
        tile[p4+3][ch] = v.w;
    }
    __syncthreads();
    #pragma unroll
    for (int k=0;k<2;k++) {
        int e = k*256 + t;
        int px = e >> 3;
        int c8 = (e & 7)*8;
        __hip_bfloat16 v[8];
        #pragma unroll
        for (int j=0;j<8;j++) v[j] = __float2bfloat16(tile[px][c8+j]);
        *(uint4*)(xt + ((size_t)(n*262144 + p0 + px))*64 + c8) = *(uint4*)v;
    }
}

// ---------------- K1b: MFMA implicit-GEMM conv -> y NHWC fp32 (+ReLU) -----------------
__global__ __launch_bounds__(256) void k_conv_mfma(
    const __hip_bfloat16* __restrict__ xt, const float* __restrict__ ws,
    float* __restrict__ y)
{
    const __hip_bfloat16* wf = (const __hip_bfloat16*)(ws + O_WFRAG);
    int t = threadIdx.x, lane = t & 63, wv = t >> 6;
    int bid = blockIdx.x;
    int nbk = (bid & 7) * (gridDim.x >> 3) + (bid >> 3);
    int pix0 = nbk*64 + wv*16;
    int n = pix0 >> 16;
    int hw = pix0 & 65535;
    int h = hw >> 8, wo0 = hw & 255;
    int m = lane & 15, q = lane >> 4;
    floatx4 acc[4] = {};
    #pragma unroll
    for (int kh=0; kh<3; kh++) {
        int ih = 2*h + kh - 1;
        if (ih < 0) continue;
        size_t rowbase = ((size_t)(n*512 + ih))*512;
        #pragma unroll
        for (int kw=0; kw<3; kw++) {
            int iw = 2*wo0 + kw - 1 + 2*m;
            bool inval = iw < 0;
            int iwc = inval ? 0 : iw;
            const __hip_bfloat16* ap = xt + (rowbase + iwc)*64 + q*8;
            const __hip_bfloat16* bp = wf + (kh*3 + kw)*4096 + lane*8;
            #pragma unroll
            for (int ks=0; ks<2; ks++) {
                uint4 au = *(const uint4*)(ap + ks*32);
                if (inval) au = make_uint4(0,0,0,0);
                bf16x8v av = __builtin_bit_cast(bf16x8v, au);
                #pragma unroll
                for (int nt=0; nt<4; nt++) {
                    uint4 bu = *(const uint4*)(bp + ks*2048 + nt*512);
                    bf16x8v bv = __builtin_bit_cast(bf16x8v, bu);
                    acc[nt] = __builtin_amdgcn_mfma_f32_16x16x32_bf16(av, bv, acc[nt], 0,0,0);
                }
            }
        }
    }
    int co0 = lane & 15;
    #pragma unroll
    for (int nt=0; nt<4; nt++)
        #pragma unroll
        for (int r=0; r<4; r++)
            y[((size_t)(pix0 + q*4 + r))*64 + nt*16 + co0] = fmaxf(acc[nt][r], 0.f);
}

// ---------------- K3: dwconv + LN + GELU -> MFMA proj -> offsets + softmax mask -------
//   512-thread / 8-wave version for FULL occupancy (LDS 36KB caps blocks at 4/CU;
//   8 waves/block -> 32 waves/CU vs previous 16). Work split keeps every FP op in
//   its exact previous order (bit-identical):
//     1a: 8 waves x 8 px (same per-px code)          -> barrier
//     1b: waves 0-3 run the unchanged 16-px LN+GELU  -> barrier
//     2 : waves 0-3 offset/mask MFMA ; waves 4-7 x_proj MFMA (now parallel) -> barrier
//     3 : waves 4-7 softmax (unchanged code)
__global__ __launch_bounds__(512) void k_branch(
    const float* __restrict__ y, const float* __restrict__ ws,
    float* __restrict__ offs, float* __restrict__ mask, float* __restrict__ xp)
{
    __shared__ float scr[64][68];                         // accs, later logits [g*12+qq]
    __shared__ __align__(16) __hip_bfloat16 x1b[64][72];  // GELU out, bf16 (proj A-frags)
    __shared__ __align__(16) __hip_bfloat16 ysb[64][72];  // center-tap y, bf16 (x_proj A)
    int t = threadIdx.x;
    int lane = t & 63;
    int wv = t >> 6;                     // 0..7
    int bid = blockIdx.x;
    int nbk = (bid & 7) * (gridDim.x >> 3) + (bid >> 3);
    int pix0 = nbk * 64;                 // 64 consecutive pixels, same image row
    int n  = pix0 >> 16;
    int hw = pix0 & 65535;
    int hh = hw >> 8, ww0 = hw & 255;
    float dwv[9];
    #pragma unroll
    for (int k=0;k<9;k++) dwv[k] = ws[O_DWW + k*C + lane];
    float dbb = ws[O_DWB + lane];
    // phase 1a: wave wv computes 8 px (2 groups of 4) with shared column loads
    const float* ybase = y + (size_t)(n*H)*W*C + lane;
    #pragma unroll
    for (int rg=0; rg<2; rg++) {
        int i0 = wv*8 + rg*4;
        int cb = ww0 + i0 - 1;
        float cc[3][6];
        #pragma unroll
        for (int kh=0; kh<3; kh++) {
            int yh = hh + kh - 1;
            bool rv = (yh >= 0) && (yh < H);
            const float* yr = ybase + (size_t)(rv ? yh : 0)*W*C;
            #pragma unroll
            for (int c=0; c<6; c++) {
                int col = cb + c;
                bool ok = rv && (col >= 0) && (col < W);
                cc[kh][c] = ok ? yr[(ptrdiff_t)col*C] : 0.f;
            }
        }
        float a[4];
        #pragma unroll
        for (int u=0; u<4; u++) a[u] = dbb;
        #pragma unroll
        for (int kh=0; kh<3; kh++)
            #pragma unroll
            for (int kw=0; kw<3; kw++) {
                float wg = dwv[kh*3+kw];
                #pragma unroll
                for (int u=0; u<4; u++) a[u] = fmaf(cc[kh][u+kw], wg, a[u]);
            }
        #pragma unroll
        for (int u=0; u<4; u++) {
            scr[i0+u][lane] = a[u];
            ysb[i0+u][lane] = __float2bfloat16(cc[1][u+1]);   // center tap, always valid
        }
    }
    __syncthreads();
    // phase 1b: waves 0-3, LN stats + GELU; lane -> (px = lane>>2, ch chunk = (lane&3)*16)
    if (wv < 4) {
        int pxl = lane >> 2;
        int cq  = lane & 3;
        int i   = wv*16 + pxl;
        const float* ar = &scr[i][cq*16];
        float4 V0 = *(const float4*)(ar);
        float4 V1 = *(const float4*)(ar + 4);
        float4 V2 = *(const float4*)(ar + 8);
        float4 V3 = *(const float4*)(ar + 12);
        float v[16] = {V0.x,V0.y,V0.z,V0.w, V1.x,V1.y,V1.z,V1.w,
                       V2.x,V2.y,V2.z,V2.w, V3.x,V3.y,V3.z,V3.w};
        float s = 0.f, s2 = 0.f;
        #pragma unroll
        for (int k=0;k<16;k++) { s += v[k]; s2 = fmaf(v[k], v[k], s2); }
        s  += __shfl_xor(s,  1, 64);  s  += __shfl_xor(s,  2, 64);
        s2 += __shfl_xor(s2, 1, 64);  s2 += __shfl_xor(s2, 2, 64);
        float mean = s * 0.015625f;
        float var  = fmaxf(fmaf(-mean, mean, s2 * 0.015625f), 0.f);
        float rsig = rsqrtf(var + 1e-5f);
        const float* gp = ws + O_LNG + cq*16;
        const float* bp = ws + O_LNB + cq*16;
        float4 Ga = *(const float4*)gp,      Gb = *(const float4*)(gp+4);
        float4 Gc = *(const float4*)(gp+8),  Gd = *(const float4*)(gp+12);
        float4 Ba = *(const float4*)bp,      Bb = *(const float4*)(bp+4);
        float4 Bc = *(const float4*)(bp+8),  Bd = *(const float4*)(bp+12);
        float gv[16] = {Ga.x,Ga.y,Ga.z,Ga.w, Gb.x,Gb.y,Gb.z,Gb.w,
                        Gc.x,Gc.y,Gc.z,Gc.w, Gd.x,Gd.y,Gd.z,Gd.w};
        float bv[16] = {Ba.x,Ba.y,Ba.z,Ba.w, Bb.x,Bb.y,Bb.z,Bb.w,
                        Bc.x,Bc.y,Bc.z,Bc.w, Bd.x,Bd.y,Bd.z,Bd.w};
        float gl[16];
        #pragma unroll
        for (int k=0;k<16;k++) {
            float xh = fmaf((v[k]-mean)*rsig, gv[k], bv[k]);
            gl[k] = 0.5f * xh * (1.f + erff(xh * 0.70710678118654752f));
        }
        uint4 w0, w1;
        w0.x = pkbf(gl[0],gl[1]);  w0.y = pkbf(gl[2],gl[3]);
        w0.z = pkbf(gl[4],gl[5]);  w0.w = pkbf(gl[6],gl[7]);
        w1.x = pkbf(gl[8],gl[9]);  w1.y = pkbf(gl[10],gl[11]);
        w1.z = pkbf(gl[12],gl[13]);w1.w = pkbf(gl[14],gl[15]);
        *(uint4*)&x1b[i][cq*16]     = w0;
        *(uint4*)&x1b[i][cq*16 + 8] = w1;
    }
    __syncthreads();
    // phase 2: waves 0-3 offset/mask MFMA; waves 4-7 x_proj MFMA (parallel)
    int m = lane & 15, q = lane >> 4;
    if (wv < 4) {
        bf16x8v af[2];
        #pragma unroll
        for (int ks=0; ks<2; ks++)
            af[ks] = __builtin_bit_cast(bf16x8v, *(const uint4*)&x1b[wv*16 + m][ks*32 + q*8]);
        const __hip_bfloat16* wcomb = (const __hip_bfloat16*)(ws + O_WCOMB);
        #pragma unroll
        for (int nt=0; nt<7; nt++) {
            int j = nt*16 + m;
            float b = (j < 72) ? ws[O_BOFF + j] : (j < 108 ? ws[O_BMASK + j - 72] : 0.f);
            floatx4 acc = {b,b,b,b};
            #pragma unroll
            for (int ks=0; ks<2; ks++) {
                uint4 bu = *(const uint4*)(wcomb + (ks*7 + nt)*512 + lane*8);
                bf16x8v bvv = __builtin_bit_cast(bf16x8v, bu);
                acc = __builtin_amdgcn_mfma_f32_16x16x32_bf16(af[ks], bvv, acc, 0,0,0);
            }
            if (j < 72) {
                #pragma unroll
                for (int r=0;r<4;r++)
                    offs[(size_t)(pix0 + wv*16 + q*4 + r)*72 + j] = acc[r];
            } else if (j < 108) {
                int jj = j - 72;               // 0..35
                int gg = jj / 9, qq = jj - gg*9;
                #pragma unroll
                for (int r=0;r<4;r++)
                    scr[wv*16 + q*4 + r][gg*12 + qq] = acc[r];   // logits overlay
            }
        }
    } else {
        int w2 = wv - 4;
        const __hip_bfloat16* wfin = (const __hip_bfloat16*)(ws + O_WINF);
        bf16x8v af2[2];
        #pragma unroll
        for (int ks=0; ks<2; ks++) {
            uint4 u = *(const uint4*)&ysb[w2*16 + m][ks*32 + q*8];
            af2[ks] = __builtin_bit_cast(bf16x8v, u);
        }
        #pragma unroll
        for (int nt=0; nt<4; nt++) {
            float b = ws[O_BIN + nt*16 + m];
            floatx4 a2 = {b,b,b,b};
            #pragma unroll
            for (int ks=0; ks<2; ks++) {
                uint4 bu = *(const uint4*)(wfin + (ks*4 + nt)*512 + lane*8);
                bf16x8v bvv = __builtin_bit_cast(bf16x8v, bu);
                a2 = __builtin_amdgcn_mfma_f32_16x16x32_bf16(af2[ks], bvv, a2, 0,0,0);
            }
            #pragma unroll
            for (int r=0;r<4;r++)
                xp[((size_t)(pix0 + w2*16 + q*4 + r))*64 + nt*16 + m] = a2[r];
        }
    }
    __syncthreads();
    // phase 3: waves 4-7, softmax; one lane per (px,g): 9 exp
    if (wv >= 4) {
        int w2 = wv - 4;
        int pxl = lane >> 2;
        int i   = w2*16 + pxl;
        int g   = lane & 3;
        const float* lrow = &scr[i][g*12];
        float l[9];
        #pragma unroll
        for (int qq=0;qq<9;qq++) l[qq] = lrow[qq];
        float mx = l[0];
        #pragma unroll
        for (int qq=1;qq<9;qq++) mx = fmaxf(mx, l[qq]);
        float e[9]; float sum = 0.f;
        #pragma unroll
        for (int qq=0;qq<9;qq++) { e[qq] = expf(l[qq]-mx); sum += e[qq]; }
        float rs = 1.f / sum;
        float* mp = mask + (size_t)(pix0 + i)*36 + g*9;
        #pragma unroll
        for (int qq=0;qq<9;qq++) mp[qq] = e[qq] * rs;
    }
}

// ---------------- K4: DCN bilinear gather + split-fp32 MFMA out-proj + NCHW write -----
#define DPX 16
__global__ __launch_bounds__(256, 4) void k_dcn(
    const float* __restrict__ xp, const float* __restrict__ offs,
    const float* __restrict__ mask, const float* __restrict__ ws,
    float* __restrict__ out)
{
    __shared__ float core[DPX][68];
    __shared__ __align__(16) float offsl[DPX*72];   // 4608B
    __shared__ __align__(16) float maskl[DPX*36];   // 2304B
    int t = threadIdx.x;
    int lane = t & 63;
    int wv = t >> 6;
    int bid = blockIdx.x;
    int nbk = (bid & 7) * (gridDim.x >> 3) + (bid >> 3);
    int pix0 = nbk * DPX;
    // stage offs (288 float4) + mask (144 float4), coalesced
    {
        const float4* osrc = (const float4*)(offs + (size_t)pix0*72);
        float4* odst = (float4*)offsl;
        odst[t] = osrc[t];
        if (t < 32) odst[256 + t] = osrc[256 + t];
        const float4* msrc = (const float4*)(mask + (size_t)pix0*36);
        float4* mdst = (float4*)maskl;
        if (t < 144) mdst[t] = msrc[t];
    }
    __syncthreads();
    int c4  = lane & 3;
    int g   = (lane >> 2) & 3;
    int sub = lane >> 4;
    int i   = wv*4 + sub;
    int pix = pix0 + i;
    int n  = pix >> 16;
    int hw = pix & 65535;
    int hh = hw >> 8, ww = hw & 255;
    const float* ob  = offsl + i*72 + g*18;
    const float* mb  = maskl + i*36 + g*9;
    const float* xpb = xp + (size_t)n*H*W*C + g*GC + c4*4;
    // phase A: ALL corner offsets + weights into static-indexed register arrays
    int   eo[P][4];
    float wv4[P][4];
    #pragma unroll
    for (int p=0;p<P;p++) {
        const int kx = p/3, ky = p%3;
        float offx = ob[p*2], offy = ob[p*2+1];
        float mm = mb[p];
        float ix = (float)(ww + kx) + offx;
        float iy = (float)(hh + ky) + offy;
        float x0f = floorf(ix), y0f = floorf(iy);
        float fx = ix - x0f, fy = iy - y0f;
        int x0 = (int)x0f - 1, y0 = (int)y0f - 1;
        int x1 = x0 + 1,       y1 = y0 + 1;
        bool vx0 = (x0 >= 0) & (x0 < W), vx1 = (x1 >= 0) & (x1 < W);
        bool vy0 = (y0 >= 0) & (y0 < H), vy1 = (y1 >= 0) & (y1 < H);
        int cx0 = min(max(x0,0), W-1), cx1 = min(max(x1,0), W-1);
        int ry0 = min(max(y0,0), H-1) * W, ry1 = min(max(y1,0), H-1) * W;
        float am = (1.f - fy) * mm, bm = fy * mm;
        float fxc = 1.f - fx;
        eo[p][0] = (ry0 + cx0) * C;  wv4[p][0] = (vy0 & vx0) ? am * fxc : 0.f;
        eo[p][1] = (ry0 + cx1) * C;  wv4[p][1] = (vy0 & vx1) ? am * fx  : 0.f;
        eo[p][2] = (ry1 + cx0) * C;  wv4[p][2] = (vy1 & vx0) ? bm * fxc : 0.f;
        eo[p][3] = (ry1 + cx1) * C;  wv4[p][3] = (vy1 & vx1) ? bm * fx  : 0.f;
    }
    // phase B: pure load+FMA stream, dual accumulators (corner pairs)
    floatx4 ac0 = {0.f,0.f,0.f,0.f}, ac1 = {0.f,0.f,0.f,0.f};
    #pragma unroll
    for (int p=0;p<P;p++) {
        float4 v0 = *(const float4*)(xpb + eo[p][0]);
        float4 v1 = *(const float4*)(xpb + eo[p][1]);
        float4 v2 = *(const float4*)(xpb + eo[p][2]);
        float4 v3 = *(const float4*)(xpb + eo[p][3]);
        float w0 = wv4[p][0], w1 = wv4[p][1], w2 = wv4[p][2], w3 = wv4[p][3];
        ac0[0] = fmaf(v0.x, w0, fmaf(v1.x, w1, ac0[0]));
        ac0[1] = fmaf(v0.y, w0, fmaf(v1.y, w1, ac0[1]));
        ac0[2] = fmaf(v0.z, w0, fmaf(v1.z, w1, ac0[2]));
        ac0[3] = fmaf(v0.w, w0, fmaf(v1.w, w1, ac0[3]));
        ac1[0] = fmaf(v2.x, w2, fmaf(v3.x, w3, ac1[0]));
        ac1[1] = fmaf(v2.y, w2, fmaf(v3.y, w3, ac1[1]));
        ac1[2] = fmaf(v2.z, w2, fmaf(v3.z, w3, ac1[2]));
        ac1[3] = fmaf(v2.w, w2, fmaf(v3.w, w3, ac1[3]));
    }
    float4 acc;
    acc.x = ac0[0] + ac1[0];
    acc.y = ac0[1] + ac1[1];
    acc.z = ac0[2] + ac1[2];
    acc.w = ac0[3] + ac1[3];
    *(float4*)&core[i][g*GC + c4*4] = acc;
    __syncthreads();
    // out-proj: wave wv owns co-tile [wv*16, wv*16+16). fp32-split MFMA:
    // out = ah@wh + ah@wl + al@wh (al@wl term ~2^-18 rel, dropped).
    {
        int m = lane & 15, q = lane >> 4;
        bf16x8v ah[2], al[2];
        #pragma unroll
        for (int ks=0; ks<2; ks++) {
            const float* ar = &core[m][ks*32 + q*8];
            float4 A0 = *(const float4*)ar;
            float4 A1 = *(const float4*)(ar + 4);
            float av[8] = {A0.x,A0.y,A0.z,A0.w, A1.x,A1.y,A1.z,A1.w};
            float rv[8];
            #pragma unroll
            for (int j=0;j<8;j++) {
                __hip_bfloat16 hb = __float2bfloat16(av[j]);
                rv[j] = av[j] - __bfloat162float(hb);
            }
            uint4 uh, ul;
            uh.x = pkbf(av[0],av[1]); uh.y = pkbf(av[2],av[3]);
            uh.z = pkbf(av[4],av[5]); uh.w = pkbf(av[6],av[7]);
            ul.x = pkbf(rv[0],rv[1]); ul.y = pkbf(rv[2],rv[3]);
            ul.z = pkbf(rv[4],rv[5]); ul.w = pkbf(rv[6],rv[7]);
            ah[ks] = __builtin_bit_cast(bf16x8v, uh);
            al[ks] = __builtin_bit_cast(bf16x8v, ul);
        }
        const __hip_bfloat16* wof = (const __hip_bfloat16*)(ws + O_WOUT);
        floatx4 a = {0.f,0.f,0.f,0.f};
        #pragma unroll
        for (int ks=0; ks<2; ks++) {
            uint4 bhu = *(const uint4*)(wof + (ks*4 + wv)*512 + lane*8);
            uint4 blu = *(const uint4*)(wof + 4096 + (ks*4 + wv)*512 + lane*8);
            bf16x8v bh = __builtin_bit_cast(bf16x8v, bhu);
            bf16x8v bl = __builtin_bit_cast(bf16x8v, blu);
            a = __builtin_amdgcn_mfma_f32_16x16x32_bf16(ah[ks], bh, a, 0,0,0);
            a = __builtin_amdgcn_mfma_f32_16x16x32_bf16(ah[ks], bl, a, 0,0,0);
            a = __builtin_amdgcn_mfma_f32_16x16x32_bf16(al[ks], bh, a, 0,0,0);
        }
        // D layout: col = co = wv*16+m, rows = q*4..q*4+3 (consecutive px) -> one
        // float4 NCHW store per lane.
        int co = wv*16 + m;
        float bo = ws[O_BOUT + co];
        int n2 = pix0 >> 16, hw0 = pix0 & 65535;
        float4 st;
        st.x = a[0] + bo; st.y = a[1] + bo; st.z = a[2] + bo; st.w = a[3] + bo;
        *(float4*)(out + (size_t)n2*C*65536 + (size_t)co*65536 + hw0 + q*4) = st;
    }
}

extern "C" void kernel_launch(void* const* d_in, const int* in_sizes, int n_in,
                              void* d_out, int out_size, void* d_ws, size_t ws_size,
                              hipStream_t stream)
{
    const float* x     = (const float*)d_in[0];
    const float* convw = (const float*)d_in[1];
    const float* w_in  = (const float*)d_in[2];
    const float* b_in  = (const float*)d_in[3];
    const float* dw_w  = (const float*)d_in[4];
    const float* dw_b  = (const float*)d_in[5];
    const float* ln_g  = (const float*)d_in[6];
    const float* ln_b  = (const float*)d_in[7];
    const float* w_off = (const float*)d_in[8];
    const float* b_off = (const float*)d_in[9];
    const float* w_mask= (const float*)d_in[10];
    const float* b_mask= (const float*)d_in[11];
    const float* w_out = (const float*)d_in[12];
    const float* b_out = (const float*)d_in[13];

    float* ws   = (float*)d_ws;
    float* y    = ws + O_Y;
    float* xp   = ws + O_XP;
    float* offs = ws + O_OFFS;
    float* mask = ws + O_MASK;
    __hip_bfloat16* xt = (__hip_bfloat16*)(ws + O_XP);

    k_prep<<<144, 256, 0, stream>>>(convw, w_in, b_in, dw_w, dw_b, ln_g, ln_b,
                                    w_off, b_off, w_mask, b_mask, w_out, b_out, ws);
    k_xt<<<8192, 256, 0, stream>>>(x, xt);
    k_conv_mfma<<<2048, 256, 0, stream>>>(xt, ws, y);
    k_branch<<<NPIX/64, 512, 0, stream>>>(y, ws, offs, mask, xp);
    k_dcn<<<NPIX/DPX, 256, 0, stream>>>(xp, offs, mask, ws, (float*)d_out);
}

// Round 9
// 349.387 us; speedup vs baseline: 1.0153x; 1.0153x over previous
//
#include <hip/hip_runtime.h>
#include <hip/hip_bf16.h>
#include <math.h>

#define NB 2
#define C 64
#define H 256
#define W 256
#define HIN 512
#define WIN 512
#define CIN 64
#define G 4
#define P 9
#define GC 16
#define NPIX (NB*H*W)   // 131072

typedef __attribute__((ext_vector_type(8))) __bf16 bf16x8v;
typedef __attribute__((ext_vector_type(4))) float floatx4;

// ws float offsets
#define O_WOUT   47872    // w_out MFMA B-frags: wh[4096 bf16] | wl[4096 bf16] = 4096 floats
#define O_BIN    51968    // 64
#define O_DWW    52032    // 576
#define O_DWB    52608    // 64
#define O_LNG    52672    // 64
#define O_LNB    52736    // 64
#define O_BOFF   52800    // 72
#define O_BMASK  52872    // 36
#define O_BOUT   52908    // 64
#define O_WFRAG  53248    // conv MFMA B-frags: 36864 bf16 = 18432 floats -> end 71680
#define O_WINF   71680    // w_in MFMA B-frags: 4096 bf16 = 2048 floats  -> end 73728
#define O_WCOMB  73728    // [w_off|w_mask|pad] 64x112 B-frags: 7168 bf16 = 3584 floats -> 77312
#define O_Y      77824    // 8388608 fp32 NHWC conv output
#define O_XP     (O_Y  + 8388608)
#define O_OFFS   (O_XP + 8388608)   // 9437184
#define O_MASK   (O_OFFS + 9437184) // 4718592
// xt (bf16 NHWC, 16777216 floats) overlaps [O_XP, O_XP+16777216): dead after conv;
// xp (written by k_branch, AFTER conv) / offs land there in stream order. Safe.

static __device__ __forceinline__ unsigned pkbf(float a, float b) {
    unsigned lo = __bfloat16_as_ushort(__float2bfloat16(a));
    unsigned hi = __bfloat16_as_ushort(__float2bfloat16(b));
    return lo | (hi << 16);
}

// ---------------- K0: stage weights/biases + pack all MFMA B-fragments ----------------
__global__ void k_prep(const float* __restrict__ conv_w, const float* __restrict__ w_in,
                       const float* __restrict__ b_in,
                       const float* __restrict__ dw_w, const float* __restrict__ dw_b,
                       const float* __restrict__ ln_g, const float* __restrict__ ln_b,
                       const float* __restrict__ w_off, const float* __restrict__ b_off,
                       const float* __restrict__ w_mask, const float* __restrict__ b_mask,
                       const float* __restrict__ w_out, const float* __restrict__ b_out,
                       float* __restrict__ ws)
{
    int i = blockIdx.x*256 + threadIdx.x;
    if (i < 36864) {   // conv B-frags: idx = ((tap*2+ks)*4+nt)*512 + lane*8 + j
        int j    = i & 7;
        int lane = (i >> 3) & 63;
        int nt   = (i >> 9) & 3;
        int ks   = (i >> 11) & 1;
        int tap  = i >> 12;
        int kh = tap / 3, kw = tap % 3;
        int ci = ks*32 + (lane >> 4)*8 + j;
        int co = nt*16 + (lane & 15);
        ((__hip_bfloat16*)(ws + O_WFRAG))[i] =
            __float2bfloat16(conv_w[co*576 + ci*9 + kh*3 + kw]);
    }
    if (i < 4096) {    // w_in B-frags: idx = (ks*4+nt)*512 + lane*8 + j
        int j    = i & 7;
        int lane = (i >> 3) & 63;
        int s    = i >> 9;
        int nt   = s & 3, ks = s >> 2;
        int ci = ks*32 + (lane >> 4)*8 + j;
        int co = nt*16 + (lane & 15);
        ((__hip_bfloat16*)(ws + O_WINF))[i] = __float2bfloat16(w_in[ci*64 + co]);
    }
    if (i < 4096) {    // w_out split-fp32 B-frags (hi|lo), same frag layout as O_WINF
        int j    = i & 7;
        int lane = (i >> 3) & 63;
        int s    = i >> 9;
        int nt   = s & 3, ks = s >> 2;
        int ci = ks*32 + (lane >> 4)*8 + j;
        int co = nt*16 + (lane & 15);
        float w = w_out[ci*64 + co];
        __hip_bfloat16 h = __float2bfloat16(w);
        ((__hip_bfloat16*)(ws + O_WOUT))[i]        = h;
        ((__hip_bfloat16*)(ws + O_WOUT))[4096 + i] = __float2bfloat16(w - __bfloat162float(h));
    }
    if (i < 7168) {    // combined off|mask B-frags: idx = (ks*7+nt)*512 + lane*8 + j
        int j    = i & 7;
        int lane = (i >> 3) & 63;
        int s    = i >> 9;          // 0..13
        int nt   = s % 7, ks = s / 7;
        int ci = ks*32 + (lane >> 4)*8 + j;
        int jj = nt*16 + (lane & 15);
        float v = (jj < 72) ? w_off[ci*72 + jj] : (jj < 108 ? w_mask[ci*36 + (jj-72)] : 0.f);
        ((__hip_bfloat16*)(ws + O_WCOMB))[i] = __float2bfloat16(v);
    }
    if (i < 64)   ws[O_BIN  + i] = b_in[i];
    if (i < 576)  ws[O_DWW  + i] = dw_w[i];
    if (i < 64)   ws[O_DWB  + i] = dw_b[i];
    if (i < 64)   ws[O_LNG  + i] = ln_g[i];
    if (i < 64)   ws[O_LNB  + i] = ln_b[i];
    if (i < 72)   ws[O_BOFF + i] = b_off[i];
    if (i < 36)   ws[O_BMASK+ i] = b_mask[i];
    if (i < 64)   ws[O_BOUT + i] = b_out[i];
}

// ---------------- K1a: x fp32 NCHW -> xt bf16 NHWC (LDS tile transpose) ---------------
__global__ __launch_bounds__(256) void k_xt(
    const float* __restrict__ x, __hip_bfloat16* __restrict__ xt)
{
    __shared__ float tile[64][65];
    int t = threadIdx.x;
    int b = blockIdx.x;
    int n  = b >> 12;
    int p0 = (b & 4095) * 64;
    const float* xb = x + (size_t)n*CIN*262144 + p0;
    #pragma unroll
    for (int k=0;k<4;k++) {
        int ch = k*16 + (t>>4);
        int p4 = (t&15)*4;
        float4 v = *(const float4*)(xb + (size_t)ch*262144 + p4);
        tile[p4+0][ch] = v.x;
        tile[p4+1][ch] = v.y;
        tile[p4+2][ch] = v.z;
        tile[p4+3][ch] = v.w;
    }
    __syncthreads();
    #pragma unroll
    for (int k=0;k<2;k++) {
        int e = k*256 + t;
        int px = e >> 3;
        int c8 = (e & 7)*8;
        __hip_bfloat16 v[8];
        #pragma unroll
        for (int j=0;j<8;j++) v[j] = __float2bfloat16(tile[px][c8+j]);
        *(uint4*)(xt + ((size_t)(n*262144 + p0 + px))*64 + c8) = *(uint4*)v;
    }
}

// ---------------- K1b: MFMA implicit-GEMM conv -> y NHWC fp32 (+ReLU) -----------------
//   2 A-tiles (32 px) per wave: each B-fragment load now feeds TWO MFMAs, halving the
//   dominant B-frag L1/TA stream per pixel. Per-accumulator MFMA order unchanged ->
//   y bit-identical. Grid 1024 (128 px/block), XCD-swizzled.
__global__ __launch_bounds__(256) void k_conv_mfma(
    const __hip_bfloat16* __restrict__ xt, const float* __restrict__ ws,
    float* __restrict__ y)
{
    const __hip_bfloat16* wf = (const __hip_bfloat16*)(ws + O_WFRAG);
    int t = threadIdx.x, lane = t & 63, wv = t >> 6;
    int bid = blockIdx.x;
    int nbk = (bid & 7) * (gridDim.x >> 3) + (bid >> 3);
    int pix0 = nbk*128 + wv*32;
    int n = pix0 >> 16;
    int hw = pix0 & 65535;
    int h = hw >> 8, wo0 = hw & 255;      // wo0 in {0,128}: 32 px never cross a row
    int m = lane & 15, q = lane >> 4;
    floatx4 acc[2][4] = {};
    #pragma unroll
    for (int kh=0; kh<3; kh++) {
        int ih = 2*h + kh - 1;
        if (ih < 0) continue;
        size_t rowbase = ((size_t)(n*512 + ih))*512;
        #pragma unroll
        for (int kw=0; kw<3; kw++) {
            int iw0 = 2*wo0 + kw - 1 + 2*m;       // tile 0
            int iw1 = iw0 + 32;                    // tile 1, always >= 31 (valid)
            bool inval = iw0 < 0;
            int iw0c = inval ? 0 : iw0;
            const __hip_bfloat16* ap0 = xt + (rowbase + iw0c)*64 + q*8;
            const __hip_bfloat16* ap1 = xt + (rowbase + iw1)*64 + q*8;
            const __hip_bfloat16* bp = wf + (kh*3 + kw)*4096 + lane*8;
            #pragma unroll
            for (int ks=0; ks<2; ks++) {
                uint4 au0 = *(const uint4*)(ap0 + ks*32);
                if (inval) au0 = make_uint4(0,0,0,0);
                uint4 au1 = *(const uint4*)(ap1 + ks*32);
                bf16x8v av0 = __builtin_bit_cast(bf16x8v, au0);
                bf16x8v av1 = __builtin_bit_cast(bf16x8v, au1);
                #pragma unroll
                for (int nt=0; nt<4; nt++) {
                    uint4 bu = *(const uint4*)(bp + ks*2048 + nt*512);
                    bf16x8v bv = __builtin_bit_cast(bf16x8v, bu);
                    acc[0][nt] = __builtin_amdgcn_mfma_f32_16x16x32_bf16(av0, bv, acc[0][nt], 0,0,0);
                    acc[1][nt] = __builtin_amdgcn_mfma_f32_16x16x32_bf16(av1, bv, acc[1][nt], 0,0,0);
                }
            }
        }
    }
    int co0 = lane & 15;
    #pragma unroll
    for (int tl=0; tl<2; tl++)
        #pragma unroll
        for (int nt=0; nt<4; nt++)
            #pragma unroll
            for (int r=0; r<4; r++)
                y[((size_t)(pix0 + tl*16 + q*4 + r))*64 + nt*16 + co0] = fmaxf(acc[tl][nt][r], 0.f);
}

// ---------------- K3: dwconv + LN + GELU -> MFMA proj -> offsets + softmax mask -------
//   Fully wave-private LDS pipeline (ZERO barriers). XCD-swizzled (y-row L2 locality).
//   (R7 256-thread version — the 512-thread split regressed, reverted.)
__global__ __launch_bounds__(256) void k_branch(
    const float* __restrict__ y, const float* __restrict__ ws,
    float* __restrict__ offs, float* __restrict__ mask, float* __restrict__ xp)
{
    __shared__ float scr[64][68];                         // accs, later logits [g*12+qq]
    __shared__ __align__(16) __hip_bfloat16 x1b[64][72];  // GELU out, bf16 (proj A-frags)
    __shared__ __align__(16) __hip_bfloat16 ysb[64][72];  // center-tap y, bf16 (x_proj A)
    int t = threadIdx.x;
    int lane = t & 63;
    int wv = t >> 6;
    int bid = blockIdx.x;
    int nbk = (bid & 7) * (gridDim.x >> 3) + (bid >> 3);
    int pix0 = nbk * 64;                 // 64 consecutive pixels, same image row
    int n  = pix0 >> 16;
    int hw = pix0 & 65535;
    int hh = hw >> 8, ww0 = hw & 255;
    float dwv[9];
    #pragma unroll
    for (int k=0;k<9;k++) dwv[k] = ws[O_DWW + k*C + lane];
    float dbb = ws[O_DWB + lane];
    // phase 1a: dwconv for this wave's 16 px, 4 at a time with shared column loads
    const float* ybase = y + (size_t)(n*H)*W*C + lane;
    #pragma unroll
    for (int rg=0; rg<4; rg++) {
        int i0 = wv*16 + rg*4;
        int cb = ww0 + i0 - 1;
        float cc[3][6];
        #pragma unroll
        for (int kh=0; kh<3; kh++) {
            int yh = hh + kh - 1;
            bool rv = (yh >= 0) && (yh < H);
            const float* yr = ybase + (size_t)(rv ? yh : 0)*W*C;
            #pragma unroll
            for (int c=0; c<6; c++) {
                int col = cb + c;
                bool ok = rv && (col >= 0) && (col < W);
                cc[kh][c] = ok ? yr[(ptrdiff_t)col*C] : 0.f;
            }
        }
        float a[4];
        #pragma unroll
        for (int u=0; u<4; u++) a[u] = dbb;
        #pragma unroll
        for (int kh=0; kh<3; kh++)
            #pragma unroll
            for (int kw=0; kw<3; kw++) {
                float wg = dwv[kh*3+kw];
                #pragma unroll
                for (int u=0; u<4; u++) a[u] = fmaf(cc[kh][u+kw], wg, a[u]);
            }
        #pragma unroll
        for (int u=0; u<4; u++) {
            scr[i0+u][lane] = a[u];
            ysb[i0+u][lane] = __float2bfloat16(cc[1][u+1]);   // center tap, always valid
        }
    }
    asm volatile("" ::: "memory");
    // phase 1b: LN stats + GELU; lane -> (px = lane>>2, ch chunk = (lane&3)*16)
    {
        int pxl = lane >> 2;
        int cq  = lane & 3;
        int i   = wv*16 + pxl;
        const float* ar = &scr[i][cq*16];
        float4 V0 = *(const float4*)(ar);
        float4 V1 = *(const float4*)(ar + 4);
        float4 V2 = *(const float4*)(ar + 8);
        float4 V3 = *(const float4*)(ar + 12);
        float v[16] = {V0.x,V0.y,V0.z,V0.w, V1.x,V1.y,V1.z,V1.w,
                       V2.x,V2.y,V2.z,V2.w, V3.x,V3.y,V3.z,V3.w};
        float s = 0.f, s2 = 0.f;
        #pragma unroll
        for (int k=0;k<16;k++) { s += v[k]; s2 = fmaf(v[k], v[k], s2); }
        s  += __shfl_xor(s,  1, 64);  s  += __shfl_xor(s,  2, 64);
        s2 += __shfl_xor(s2, 1, 64);  s2 += __shfl_xor(s2, 2, 64);
        float mean = s * 0.015625f;
        float var  = fmaxf(fmaf(-mean, mean, s2 * 0.015625f), 0.f);
        float rsig = rsqrtf(var + 1e-5f);
        const float* gp = ws + O_LNG + cq*16;
        const float* bp = ws + O_LNB + cq*16;
        float4 Ga = *(const float4*)gp,      Gb = *(const float4*)(gp+4);
        float4 Gc = *(const float4*)(gp+8),  Gd = *(const float4*)(gp+12);
        float4 Ba = *(const float4*)bp,      Bb = *(const float4*)(bp+4);
        float4 Bc = *(const float4*)(bp+8),  Bd = *(const float4*)(bp+12);
        float gv[16] = {Ga.x,Ga.y,Ga.z,Ga.w, Gb.x,Gb.y,Gb.z,Gb.w,
                        Gc.x,Gc.y,Gc.z,Gc.w, Gd.x,Gd.y,Gd.z,Gd.w};
        float bv[16] = {Ba.x,Ba.y,Ba.z,Ba.w, Bb.x,Bb.y,Bb.z,Bb.w,
                        Bc.x,Bc.y,Bc.z,Bc.w, Bd.x,Bd.y,Bd.z,Bd.w};
        float gl[16];
        #pragma unroll
        for (int k=0;k<16;k++) {
            float xh = fmaf((v[k]-mean)*rsig, gv[k], bv[k]);
            gl[k] = 0.5f * xh * (1.f + erff(xh * 0.70710678118654752f));
        }
        uint4 w0, w1;
        w0.x = pkbf(gl[0],gl[1]);  w0.y = pkbf(gl[2],gl[3]);
        w0.z = pkbf(gl[4],gl[5]);  w0.w = pkbf(gl[6],gl[7]);
        w1.x = pkbf(gl[8],gl[9]);  w1.y = pkbf(gl[10],gl[11]);
        w1.z = pkbf(gl[12],gl[13]);w1.w = pkbf(gl[14],gl[15]);
        *(uint4*)&x1b[i][cq*16]     = w0;
        *(uint4*)&x1b[i][cq*16 + 8] = w1;
    }
    asm volatile("" ::: "memory");
    // phase 2: offset/mask MFMA (A-frags straight from x1b)
    int m = lane & 15, q = lane >> 4;
    bf16x8v af[2];
    #pragma unroll
    for (int ks=0; ks<2; ks++)
        af[ks] = __builtin_bit_cast(bf16x8v, *(const uint4*)&x1b[wv*16 + m][ks*32 + q*8]);
    const __hip_bfloat16* wcomb = (const __hip_bfloat16*)(ws + O_WCOMB);
    #pragma unroll
    for (int nt=0; nt<7; nt++) {
        int j = nt*16 + m;
        float b = (j < 72) ? ws[O_BOFF + j] : (j < 108 ? ws[O_BMASK + j - 72] : 0.f);
        floatx4 acc = {b,b,b,b};
        #pragma unroll
        for (int ks=0; ks<2; ks++) {
            uint4 bu = *(const uint4*)(wcomb + (ks*7 + nt)*512 + lane*8);
            bf16x8v bvv = __builtin_bit_cast(bf16x8v, bu);
            acc = __builtin_amdgcn_mfma_f32_16x16x32_bf16(af[ks], bvv, acc, 0,0,0);
        }
        if (j < 72) {
            #pragma unroll
            for (int r=0;r<4;r++)
                offs[(size_t)(pix0 + wv*16 + q*4 + r)*72 + j] = acc[r];
        } else if (j < 108) {
            int jj = j - 72;               // 0..35
            int gg = jj / 9, qq = jj - gg*9;
            #pragma unroll
            for (int r=0;r<4;r++)
                scr[wv*16 + q*4 + r][gg*12 + qq] = acc[r];   // logits overlay (own rows)
        }
    }
    // phase 2b: x_proj MFMA for this wave's 16 pixels (wave-private ysb rows)
    {
        const __hip_bfloat16* wfin = (const __hip_bfloat16*)(ws + O_WINF);
        bf16x8v af2[2];
        #pragma unroll
        for (int ks=0; ks<2; ks++) {
            uint4 u = *(const uint4*)&ysb[wv*16 + m][ks*32 + q*8];
            af2[ks] = __builtin_bit_cast(bf16x8v, u);
        }
        #pragma unroll
        for (int nt=0; nt<4; nt++) {
            float b = ws[O_BIN + nt*16 + m];
            floatx4 a2 = {b,b,b,b};
            #pragma unroll
            for (int ks=0; ks<2; ks++) {
                uint4 bu = *(const uint4*)(wfin + (ks*4 + nt)*512 + lane*8);
                bf16x8v bvv = __builtin_bit_cast(bf16x8v, bu);
                a2 = __builtin_amdgcn_mfma_f32_16x16x32_bf16(af2[ks], bvv, a2, 0,0,0);
            }
            #pragma unroll
            for (int r=0;r<4;r++)
                xp[((size_t)(pix0 + wv*16 + q*4 + r))*64 + nt*16 + m] = a2[r];
        }
    }
    asm volatile("" ::: "memory");
    // phase 3: softmax, one lane per (px,g): 9 exp, results reused for outputs
    {
        int pxl = lane >> 2;
        int i   = wv*16 + pxl;
        int g   = lane & 3;
        const float* lrow = &scr[i][g*12];
        float l[9];
        #pragma unroll
        for (int qq=0;qq<9;qq++) l[qq] = lrow[qq];
        float mx = l[0];
        #pragma unroll
        for (int qq=1;qq<9;qq++) mx = fmaxf(mx, l[qq]);
        float e[9]; float sum = 0.f;
        #pragma unroll
        for (int qq=0;qq<9;qq++) { e[qq] = expf(l[qq]-mx); sum += e[qq]; }
        float rs = 1.f / sum;
        float* mp = mask + (size_t)(pix0 + i)*36 + g*9;
        #pragma unroll
        for (int qq=0;qq<9;qq++) mp[qq] = e[qq] * rs;
    }
}

// ---------------- K4: DCN bilinear gather + split-fp32 MFMA out-proj + NCHW write -----
#define DPX 16
__global__ __launch_bounds__(256, 4) void k_dcn(
    const float* __restrict__ xp, const float* __restrict__ offs,
    const float* __restrict__ mask, const float* __restrict__ ws,
    float* __restrict__ out)
{
    __shared__ float core[DPX][68];
    __shared__ __align__(16) float offsl[DPX*72];   // 4608B
    __shared__ __align__(16) float maskl[DPX*36];   // 2304B
    int t = threadIdx.x;
    int lane = t & 63;
    int wv = t >> 6;
    int bid = blockIdx.x;
    int nbk = (bid & 7) * (gridDim.x >> 3) + (bid >> 3);
    int pix0 = nbk * DPX;
    // stage offs (288 float4) + mask (144 float4), coalesced
    {
        const float4* osrc = (const float4*)(offs + (size_t)pix0*72);
        float4* odst = (float4*)offsl;
        odst[t] = osrc[t];
        if (t < 32) odst[256 + t] = osrc[256 + t];
        const float4* msrc = (const float4*)(mask + (size_t)pix0*36);
        float4* mdst = (float4*)maskl;
        if (t < 144) mdst[t] = msrc[t];
    }
    __syncthreads();
    int c4  = lane & 3;
    int g   = (lane >> 2) & 3;
    int sub = lane >> 4;
    int i   = wv*4 + sub;
    int pix = pix0 + i;
    int n  = pix >> 16;
    int hw = pix & 65535;
    int hh = hw >> 8, ww = hw & 255;
    const float* ob  = offsl + i*72 + g*18;
    const float* mb  = maskl + i*36 + g*9;
    const float* xpb = xp + (size_t)n*H*W*C + g*GC + c4*4;
    // phase A: ALL corner offsets + weights into static-indexed register arrays
    int   eo[P][4];
    float wv4[P][4];
    #pragma unroll
    for (int p=0;p<P;p++) {
        const int kx = p/3, ky = p%3;
        float offx = ob[p*2], offy = ob[p*2+1];
        float mm = mb[p];
        float ix = (float)(ww + kx) + offx;
        float iy = (float)(hh + ky) + offy;
        float x0f = floorf(ix), y0f = floorf(iy);
        float fx = ix - x0f, fy = iy - y0f;
        int x0 = (int)x0f - 1, y0 = (int)y0f - 1;
        int x1 = x0 + 1,       y1 = y0 + 1;
        bool vx0 = (x0 >= 0) & (x0 < W), vx1 = (x1 >= 0) & (x1 < W);
        bool vy0 = (y0 >= 0) & (y0 < H), vy1 = (y1 >= 0) & (y1 < H);
        int cx0 = min(max(x0,0), W-1), cx1 = min(max(x1,0), W-1);
        int ry0 = min(max(y0,0), H-1) * W, ry1 = min(max(y1,0), H-1) * W;
        float am = (1.f - fy) * mm, bm = fy * mm;
        float fxc = 1.f - fx;
        eo[p][0] = (ry0 + cx0) * C;  wv4[p][0] = (vy0 & vx0) ? am * fxc : 0.f;
        eo[p][1] = (ry0 + cx1) * C;  wv4[p][1] = (vy0 & vx1) ? am * fx  : 0.f;
        eo[p][2] = (ry1 + cx0) * C;  wv4[p][2] = (vy1 & vx0) ? bm * fxc : 0.f;
        eo[p][3] = (ry1 + cx1) * C;  wv4[p][3] = (vy1 & vx1) ? bm * fx  : 0.f;
    }
    // phase B: pure load+FMA stream, dual accumulators (corner pairs)
    floatx4 ac0 = {0.f,0.f,0.f,0.f}, ac1 = {0.f,0.f,0.f,0.f};
    #pragma unroll
    for (int p=0;p<P;p++) {
        float4 v0 = *(const float4*)(xpb + eo[p][0]);
        float4 v1 = *(const float4*)(xpb + eo[p][1]);
        float4 v2 = *(const float4*)(xpb + eo[p][2]);
        float4 v3 = *(const float4*)(xpb + eo[p][3]);
        float w0 = wv4[p][0], w1 = wv4[p][1], w2 = wv4[p][2], w3 = wv4[p][3];
        ac0[0] = fmaf(v0.x, w0, fmaf(v1.x, w1, ac0[0]));
        ac0[1] = fmaf(v0.y, w0, fmaf(v1.y, w1, ac0[1]));
        ac0[2] = fmaf(v0.z, w0, fmaf(v1.z, w1, ac0[2]));
        ac0[3] = fmaf(v0.w, w0, fmaf(v1.w, w1, ac0[3]));
        ac1[0] = fmaf(v2.x, w2, fmaf(v3.x, w3, ac1[0]));
        ac1[1] = fmaf(v2.y, w2, fmaf(v3.y, w3, ac1[1]));
        ac1[2] = fmaf(v2.z, w2, fmaf(v3.z, w3, ac1[2]));
        ac1[3] = fmaf(v2.w, w2, fmaf(v3.w, w3, ac1[3]));
    }
    float4 acc;
    acc.x = ac0[0] + ac1[0];
    acc.y = ac0[1] + ac1[1];
    acc.z = ac0[2] + ac1[2];
    acc.w = ac0[3] + ac1[3];
    *(float4*)&core[i][g*GC + c4*4] = acc;
    __syncthreads();
    // out-proj: wave wv owns co-tile [wv*16, wv*16+16). fp32-split MFMA:
    // out = ah@wh + ah@wl + al@wh (al@wl term ~2^-18 rel, dropped).
    {
        int m = lane & 15, q = lane >> 4;
        bf16x8v ah[2], al[2];
        #pragma unroll
        for (int ks=0; ks<2; ks++) {
            const float* ar = &core[m][ks*32 + q*8];
            float4 A0 = *(const float4*)ar;
            float4 A1 = *(const float4*)(ar + 4);
            float av[8] = {A0.x,A0.y,A0.z,A0.w, A1.x,A1.y,A1.z,A1.w};
            float rv[8];
            #pragma unroll
            for (int j=0;j<8;j++) {
                __hip_bfloat16 hb = __float2bfloat16(av[j]);
                rv[j] = av[j] - __bfloat162float(hb);
            }
            uint4 uh, ul;
            uh.x = pkbf(av[0],av[1]); uh.y = pkbf(av[2],av[3]);
            uh.z = pkbf(av[4],av[5]); uh.w = pkbf(av[6],av[7]);
            ul.x = pkbf(rv[0],rv[1]); ul.y = pkbf(rv[2],rv[3]);
            ul.z = pkbf(rv[4],rv[5]); ul.w = pkbf(rv[6],rv[7]);
            ah[ks] = __builtin_bit_cast(bf16x8v, uh);
            al[ks] = __builtin_bit_cast(bf16x8v, ul);
        }
        const __hip_bfloat16* wof = (const __hip_bfloat16*)(ws + O_WOUT);
        floatx4 a = {0.f,0.f,0.f,0.f};
        #pragma unroll
        for (int ks=0; ks<2; ks++) {
            uint4 bhu = *(const uint4*)(wof + (ks*4 + wv)*512 + lane*8);
            uint4 blu = *(const uint4*)(wof + 4096 + (ks*4 + wv)*512 + lane*8);
            bf16x8v bh = __builtin_bit_cast(bf16x8v, bhu);
            bf16x8v bl = __builtin_bit_cast(bf16x8v, blu);
            a = __builtin_amdgcn_mfma_f32_16x16x32_bf16(ah[ks], bh, a, 0,0,0);
            a = __builtin_amdgcn_mfma_f32_16x16x32_bf16(ah[ks], bl, a, 0,0,0);
            a = __builtin_amdgcn_mfma_f32_16x16x32_bf16(al[ks], bh, a, 0,0,0);
        }
        // D layout: col = co = wv*16+m, rows = q*4..q*4+3 (consecutive px) -> one
        // float4 NCHW store per lane.
        int co = wv*16 + m;
        float bo = ws[O_BOUT + co];
        int n2 = pix0 >> 16, hw0 = pix0 & 65535;
        float4 st;
        st.x = a[0] + bo; st.y = a[1] + bo; st.z = a[2] + bo; st.w = a[3] + bo;
        *(float4*)(out + (size_t)n2*C*65536 + (size_t)co*65536 + hw0 + q*4) = st;
    }
}

extern "C" void kernel_launch(void* const* d_in, const int* in_sizes, int n_in,
                              void* d_out, int out_size, void* d_ws, size_t ws_size,
                              hipStream_t stream)
{
    const float* x     = (const float*)d_in[0];
    const float* convw = (const float*)d_in[1];
    const float* w_in  = (const float*)d_in[2];
    const float* b_in  = (const float*)d_in[3];
    const float* dw_w  = (const float*)d_in[4];
    const float* dw_b  = (const float*)d_in[5];
    const float* ln_g  = (const float*)d_in[6];
    const float* ln_b  = (const float*)d_in[7];
    const float* w_off = (const float*)d_in[8];
    const float* b_off = (const float*)d_in[9];
    const float* w_mask= (const float*)d_in[10];
    const float* b_mask= (const float*)d_in[11];
    const float* w_out = (const float*)d_in[12];
    const float* b_out = (const float*)d_in[13];

    float* ws   = (float*)d_ws;
    float* y    = ws + O_Y;
    float* xp   = ws + O_XP;
    float* offs = ws + O_OFFS;
    float* mask = ws + O_MASK;
    __hip_bfloat16* xt = (__hip_bfloat16*)(ws + O_XP);

    k_prep<<<144, 256, 0, stream>>>(convw, w_in, b_in, dw_w, dw_b, ln_g, ln_b,
                                    w_off, b_off, w_mask, b_mask, w_out, b_out, ws);
    k_xt<<<8192, 256, 0, stream>>>(x, xt);
    k_conv_mfma<<<1024, 256, 0, stream>>>(xt, ws, y);
    k_branch<<<NPIX/64, 256, 0, stream>>>(y, ws, offs, mask, xp);
    k_dcn<<<NPIX/DPX, 256, 0, stream>>>(xp, offs, mask, ws, (float*)d_out);
}